// Round 15
// baseline (782.412 us; speedup 1.0000x reference)
//
#include <hip/hip_runtime.h>
#include <stdint.h>

#define T_STEPS 256
#define EMBD 10
#define NKIT 9          // K = 288 = 9*32 (256 h + 10 x + 1 bias + pad)
#define NBLK_K1 (64 * NKIT)
#define NBLK 512        // main grid: 8 hcol-eighths x 64 batch-groups

typedef __attribute__((ext_vector_type(8))) short bf16x8;
typedef __attribute__((ext_vector_type(4))) float f32x4;
typedef __attribute__((ext_vector_type(4))) int   i32x4;

__device__ __forceinline__ unsigned short f2bf(float f) {
    union { float f; unsigned int u; } v; v.f = f;
    unsigned int u = v.u;
    unsigned int r = (u + 0x7FFFu + ((u >> 16) & 1u)) >> 16;  // RNE
    return (unsigned short)r;
}
__device__ __forceinline__ float sig_fast(float x) {
    return __builtin_amdgcn_rcpf(1.0f + __builtin_amdgcn_exp2f(-1.4426950408889634f * x));
}
__device__ __forceinline__ float tanh_fast(float x) {
    return 1.0f - 2.0f * __builtin_amdgcn_rcpf(__builtin_amdgcn_exp2f(2.8853900817779268f * x) + 1.0f);
}
__device__ __forceinline__ f32x4 mfma_v(i32x4 a, i32x4 b, f32x4 c) {
    return __builtin_amdgcn_mfma_f32_16x16x32_bf16(
        __builtin_bit_cast(bf16x8, a), __builtin_bit_cast(bf16x8, b), c, 0, 0, 0);
}

// ---------------------------------------------------------------------------
// K1: swizzled bf16 weights [kit][ntile][lane] x 16B + zero the 2 MB hxc
// (seq words must start != any expected step; zero works, expected >= 1).
// ---------------------------------------------------------------------------
__global__ __launch_bounds__(64) void build_wswz(
    const float* __restrict__ Wgx, const float* __restrict__ Wgh, const float* __restrict__ bg,
    const float* __restrict__ Wix, const float* __restrict__ Wih, const float* __restrict__ bi,
    const float* __restrict__ Wfx, const float* __restrict__ Wfh, const float* __restrict__ bf_,
    const float* __restrict__ Wox, const float* __restrict__ Woh, const float* __restrict__ bo,
    unsigned short* __restrict__ wswz, unsigned int* __restrict__ hxcz)
{
    {
        int4 z4 = {0, 0, 0, 0};
        size_t gid = (size_t)blockIdx.x * 64 + threadIdx.x;
        for (size_t i = gid; i < 131072; i += (size_t)NBLK_K1 * 64)
            ((int4*)hxcz)[i] = z4;
    }

    int g   = blockIdx.x / NKIT;   // ntile
    int kit = blockIdx.x % NKIT;
    int lane = threadIdx.x;
    int n = g * 16 + (lane & 15);
    int q = n >> 8;
    int col = n & 255;
    const float* Wh = (q == 0) ? Wgh : (q == 1) ? Wih : (q == 2) ? Wfh : Woh;
    const float* Wx = (q == 0) ? Wgx : (q == 1) ? Wix : (q == 2) ? Wfx : Wox;
    const float* bb = (q == 0) ? bg  : (q == 1) ? bi  : (q == 2) ? bf_ : bo;
    int k0 = kit * 32 + (lane >> 4) * 8;

    int4 out;
    unsigned short* p = (unsigned short*)&out;
#pragma unroll
    for (int jx = 0; jx < 8; jx++) {
        int k = k0 + jx;
        float v = 0.0f;
        if (k < 256)             v = Wh[k * 256 + col];
        else if (k < 256 + EMBD) v = Wx[(k - 256) * 256 + col];
        else if (k == 266)       v = bb[col];
        p[jx] = f2bf(v);
    }
    ((int4*)wswz)[(kit * 64 + g) * 64 + lane] = out;
}

// kit -> B source (compile-time s only; rule 20: no runtime indexing)
#define KIDX(s) ((s) <= 4 ? (s) : (s) == 7 ? 5 : 6)
#define BSRC(s) ((s) == 5 ? B_lds[(0 * 8 + gate * 2 + sub) * 64 + lane] \
               : (s) == 6 ? B_lds[(1 * 8 + gate * 2 + sub) * 64 + lane] \
               : breg[KIDX(s)])
#define DO_KIT(s) do { i32x4 a_ = ((const i32x4*)Ah_lds)[ah_rd + (s) * 4]; \
        acc = mfma_v(a_, BSRC(s), acc); } while (0)

// ---------------------------------------------------------------------------
// K2: 8-way N-SPLIT persistent LSTM. 512 blocks x 512 threads, 2/CU.
// blk = hg*64+gb: hg = hcol EIGHTH (32 cols x 4 gates = 128 z-cols), gb =
// batch group (16 rows). Per wave (gate=w>>1, sub=w&1): ONE ntile -> ONE
// 9-MFMA chain/step (R31 had 18/wave: compute segment of the serial chain
// halves; comm RT unchanged). Structural alignment: kit s consumes h-eighth
// s, so own-kit DO_KIT(hg) runs under the RT (h local in LDS) and each
// remote kit maps 1:1 to a staged eighth.
// Exchange: R30/31-verified seq-tagged u64 protocol, fire-and-forget sc1
// stores, combined-reload retry. Staging: thread tid<448 owns 4 consecutive
// u64 (slot=tid*4: eighth=slot>>8 skip-own, row=(slot>>4)&15, pair=slot&15)
// via two dwordx4. 2 blocks/CU co-residency: one group's compute overlaps
// the other's comm wait. Capacity: ~36KB LDS, 8 waves, <=128 VGPR => >=4
// blocks/CU, 512 all-resident (deadlock-safe); spin stays bounded.
// ---------------------------------------------------------------------------
__global__ __launch_bounds__(512, 4)
void lstm_main(
    const int*   __restrict__ xtok,   // [1024][1][256]
    const float* __restrict__ emb,    // [32000][10]
    const float* __restrict__ Wph,    // [256][10]
    const float* __restrict__ bp,     // [10]
    const unsigned short* __restrict__ wswz,
    unsigned long long* __restrict__ hxc,  // [2][64][16][128] u64 {seq, 2xbf16}
    float* __restrict__ out)          // [1024][10]
{
    __shared__ __align__(16) unsigned short A8_lds[2][64 * 8];  // 2 KB (kit 8: x+bias)
    __shared__ __align__(16) i32x4 B_lds[2 * 8 * 64];           // 16 KB (kits 5,6)
    __shared__ __align__(16) unsigned int Ah_lds[16 * 132];     // 8.25 KB (h, padded)
    __shared__ float z_lds[4 * 16 * 34];                        // 8.5 KB (padded 34)
    __shared__ float outacc[160];

    const int tid  = threadIdx.x;
    const int w    = tid >> 6;        // wave 0..7
    const int lane = tid & 63;
    const int blk  = blockIdx.x;
    const int gb   = blk & 63;        // batch group
    const int hg   = blk >> 6;        // hcol eighth 0..7

    const int gate = w >> 1;          // 0..3
    const int sub  = w & 1;           // 16-col subtile within the eighth

    const int m_x = tid >> 4;         // x-gather row (tid<256)
    const int e_x = tid & 15;

    const int r_gm = tid >> 4;        // gate-math row (tid<256)
    const int hc0  = (tid & 15) * 2;  // gate-math col pair base within eighth

    const i32x4* Bg = (const i32x4*)wswz;

    // --- B prologue: regs for kits {0,1,2,3,4,7,8} (28 VGPRs) ---
    i32x4 breg[7];
    {
        const int ks[7] = {0, 1, 2, 3, 4, 7, 8};
        const int ntile = gate * 16 + hg * 2 + sub;
#pragma unroll
        for (int i = 0; i < 7; i++)
            breg[i] = Bg[(ks[i] * 64 + ntile) * 64 + lane];
    }
    // --- B LDS: kits 5,6 for this block's 8 ntiles ---
    for (int i = tid; i < 2 * 8 * 64; i += 512) {
        int k   = i >> 9;           // 0->kit5, 1->kit6
        int ntl = (i >> 6) & 7;     // local ntile = gt*2 + sb
        int ln  = i & 63;
        int gt = ntl >> 1, sb = ntl & 1;
        B_lds[i] = Bg[((5 + k) * 64 + gt * 16 + hg * 2 + sb) * 64 + ln];
    }

    // --- A8 init: zeros, bias (both parities), x_0 (parity 0) ---
    {
        int4 z4 = {0, 0, 0, 0};
        if (tid < 128) ((int4*)A8_lds)[tid] = z4;
    }
    __syncthreads();
    if (tid < 16) {
        A8_lds[0][(16 + tid) * 8 + 2] = 0x3F80;  // bias=1.0 at k-local=10
        A8_lds[1][(16 + tid) * 8 + 2] = 0x3F80;
    }
    if (tid < 256 && e_x < EMBD) {
        int tok = xtok[(gb * 16 + m_x) * T_STEPS + 0];
        float v = emb[tok * EMBD + e_x];
        A8_lds[0][(m_x + 16 * (e_x >> 3)) * 8 + (e_x & 7)] = f2bf(v);
    }
    __syncthreads();

    float c0 = 0.0f, c1 = 0.0f;

    // af LDS read base (i32x4 units): row (lane&15)*33 + quad; kit s at +4s
    const int ah_rd = (lane & 15) * 33 + (lane >> 4);
    // staging map: 4 consecutive u64 per thread (tid<448)
    const bool do_st = (tid < 448);
    const int s0    = tid * 4;
    const int e_    = s0 >> 8;                 // 0..6
    const int re    = e_ + (e_ >= hg ? 1 : 0); // skip own eighth
    const int srow  = (s0 >> 4) & 15;
    const int spair = s0 & 15;                 // 0,4,8,12
    const int st_off = srow * 128 + re * 16 + spair;  // u64 units
    const int ah_st  = srow * 132 + re * 16 + spair;  // u32 units

    for (int t = 0; t < T_STEPS; t++) {
        const int p = t & 1, q = (t + 1) & 1;

        // x(t+1) prefetch (independent)
        float xval = 0.0f;
        const bool do_x = (t < T_STEPS - 1) && (tid < 256) && (e_x < EMBD);
        if ((t < T_STEPS - 1) && (tid < 256)) {
            int tok = xtok[(gb * 16 + m_x) * T_STEPS + (t + 1)];
            if (e_x < EMBD) xval = emb[tok * EMBD + e_x];
        }

        const unsigned long long* hb = hxc + (size_t)(p * 64 + gb) * 2048;
        i32x4 va, vb;

        // ISSUE remote h(t) loads -- no wait, in flight across the barrier
        if (t > 0 && do_st) {
            asm volatile("global_load_dwordx4 %0, %2, off sc1\n\t"
                         "global_load_dwordx4 %1, %2, off offset:16 sc1"
                         : "=&v"(va), "=&v"(vb)
                         : "v"(hb + st_off) : "memory");
        }

        // LAND-own: raw barrier, LDS-only wait (keeps vmem in flight)
        asm volatile("s_waitcnt lgkmcnt(0)" ::: "memory");
        __builtin_amdgcn_s_barrier();

        f32x4 acc = (f32x4){0.f, 0.f, 0.f, 0.f};
        // kit 8 (x + bias) -- h-independent
        {
            i32x4 a8 = ((const i32x4*)A8_lds[p])[lane];
            acc = mfma_v(a8, breg[6], acc);
        }

        if (t > 0) {
            // own kit (h-eighth hg is local in LDS) under the RT.
            // block-uniform hg: static dispatch (rule 20)
            if      (hg == 0) DO_KIT(0);
            else if (hg == 1) DO_KIT(1);
            else if (hg == 2) DO_KIT(2);
            else if (hg == 3) DO_KIT(3);
            else if (hg == 4) DO_KIT(4);
            else if (hg == 5) DO_KIT(5);
            else if (hg == 6) DO_KIT(6);
            else              DO_KIT(7);

            if (do_st) {
                // validate: wait threaded through va/vb (orders reg reads)
                asm volatile("s_waitcnt vmcnt(0)" : "+v"(va), "+v"(vb) :: "memory");
                int spins = 0;
                while ((va.y != t || va.w != t || vb.y != t || vb.w != t) &&
                       spins < 200000) {
                    ++spins;
                    __builtin_amdgcn_s_sleep(1);
                    // combined reload: both dwordx4 overlapped (R31-proven)
                    asm volatile("global_load_dwordx4 %0, %2, off sc1\n\t"
                                 "global_load_dwordx4 %1, %2, off offset:16 sc1\n\t"
                                 "s_waitcnt vmcnt(0)"
                                 : "=&v"(va), "=&v"(vb)
                                 : "v"(hb + st_off) : "memory");
                }
                Ah_lds[ah_st + 0] = (unsigned int)va.x;
                Ah_lds[ah_st + 1] = (unsigned int)va.z;
                Ah_lds[ah_st + 2] = (unsigned int)vb.x;
                Ah_lds[ah_st + 3] = (unsigned int)vb.z;
            }
            // LAND-remote: raw barrier, LDS-only wait
            asm volatile("s_waitcnt lgkmcnt(0)" ::: "memory");
            __builtin_amdgcn_s_barrier();

            // 7 remote kits (own already done)
            if (hg != 0) DO_KIT(0);
            if (hg != 1) DO_KIT(1);
            if (hg != 2) DO_KIT(2);
            if (hg != 3) DO_KIT(3);
            if (hg != 4) DO_KIT(4);
            if (hg != 5) DO_KIT(5);
            if (hg != 6) DO_KIT(6);
            if (hg != 7) DO_KIT(7);
        }

        // z -> z_lds (C layout: batch row m = (lane>>4)*4+reg, ncol = lane&15)
        {
            const int col = lane & 15, qd = lane >> 4;
#pragma unroll
            for (int rr = 0; rr < 4; rr++)
                z_lds[(gate * 16 + qd * 4 + rr) * 34 + sub * 16 + col] = acc[rr];
        }
        __syncthreads();  // B1: z complete (af reads also retired)

        // gate math: 2 h-values per thread (row r_gm, eighth-cols hc0/hc0+1)
        float hh0 = 0.f, hh1 = 0.f;
        if (tid < 256) {
            float zg[4], zh[4];
#pragma unroll
            for (int g = 0; g < 4; g++) {
                const float2 zz = *(const float2*)&z_lds[(g * 16 + r_gm) * 34 + hc0];
                zg[g] = zz.x; zh[g] = zz.y;
            }
            {
                float gg = tanh_fast(zg[0]), ii = sig_fast(zg[1]);
                float ff = sig_fast(zg[2]),  oo = sig_fast(zg[3]);
                float cn = gg * ii + c0 * ff; c0 = cn;
                hh0 = tanh_fast(cn) * oo;
            }
            {
                float gg = tanh_fast(zh[0]), ii = sig_fast(zh[1]);
                float ff = sig_fast(zh[2]),  oo = sig_fast(zh[3]);
                float cn = gg * ii + c1 * ff; c1 = cn;
                hh1 = tanh_fast(cn) * oo;
            }
        }

        if (t < T_STEPS - 1) {
            if (tid < 256) {
                unsigned int hp;
                asm("v_cvt_pk_bf16_f32 %0, %1, %2" : "=v"(hp) : "v"(hh0), "v"(hh1));
                // own eighth straight to LDS (consumed after next LAND-own)
                Ah_lds[r_gm * 132 + hg * 16 + (hc0 >> 1)] = hp;
                // fire-and-forget seq-tagged u64 (no drain, no flag)
                unsigned long long pv =
                    ((unsigned long long)(unsigned int)(t + 1) << 32) |
                    (unsigned long long)hp;
                unsigned long long* dst =
                    hxc + (size_t)(q * 64 + gb) * 2048 + r_gm * 128 + hg * 16 + (hc0 >> 1);
                asm volatile("global_store_dwordx2 %0, %1, off sc1"
                             :: "v"(dst), "v"(pv) : "memory");
            }
            if (do_x)
                A8_lds[q][(m_x + 16 * (e_x >> 3)) * 8 + (e_x & 7)] = f2bf(xval);
        } else {
            // --- epilogue: project final h (held in hh0/hh1) ---
            if (tid < 160) outacc[tid] = 0.0f;
            __syncthreads();
            if (tid < 256) {
                const int hcg = hg * 32 + hc0;
                float part[10];
#pragma unroll
                for (int cl = 0; cl < 10; cl++)
                    part[cl] = hh0 * Wph[hcg * 10 + cl] + hh1 * Wph[(hcg + 1) * 10 + cl];
#pragma unroll
                for (int cl = 0; cl < 10; cl++)
                    atomicAdd(&outacc[r_gm * 10 + cl], part[cl]);
            }
            __syncthreads();
            if (tid < 160) {
                int m = tid / 10, cl = tid - m * 10;
                float v = outacc[tid];
                if (hg == 0) v += bp[cl];     // bias added exactly once per row
                atomicAdd(&out[(gb * 16 + m) * 10 + cl], v);
            }
        }
    }
}

extern "C" void kernel_launch(void* const* d_in, const int* in_sizes, int n_in,
                              void* d_out, int out_size, void* d_ws, size_t ws_size,
                              hipStream_t stream) {
    const int*   x    = (const int*)  d_in[0];
    const float* emb  = (const float*)d_in[1];
    const float* Wgx  = (const float*)d_in[2];
    const float* Wgh  = (const float*)d_in[3];
    const float* bg   = (const float*)d_in[4];
    const float* Wix  = (const float*)d_in[5];
    const float* Wih  = (const float*)d_in[6];
    const float* bi   = (const float*)d_in[7];
    const float* Wfx  = (const float*)d_in[8];
    const float* Wfh  = (const float*)d_in[9];
    const float* bf_  = (const float*)d_in[10];
    const float* Wox  = (const float*)d_in[11];
    const float* Woh  = (const float*)d_in[12];
    const float* bo   = (const float*)d_in[13];
    const float* Wph  = (const float*)d_in[14];
    const float* bp   = (const float*)d_in[15];

    char* ws = (char*)d_ws;
    unsigned short*     wswz = (unsigned short*)ws;                 // 576 KB
    unsigned long long* hxc  = (unsigned long long*)(ws + 589824 + 4096); // 2 MB

    build_wswz<<<NBLK_K1, 64, 0, stream>>>(Wgx, Wgh, bg, Wix, Wih, bi,
                                           Wfx, Wfh, bf_, Wox, Woh, bo,
                                           wswz, (unsigned int*)hxc);
    lstm_main<<<NBLK, 512, 0, stream>>>(x, emb, Wph, bp, wswz, hxc,
                                        (float*)d_out);
}

// Round 17
// 555.206 us; speedup vs baseline: 1.4092x; 1.4092x over previous
//
#include <hip/hip_runtime.h>
#include <stdint.h>

#define T_STEPS 256
#define EMBD 10
#define NKIT 9          // K = 288 = 9*32 (256 h + 10 x + 1 bias + pad)
#define NBLK_K1 (64 * NKIT)
#define NBLK 256        // main grid: 4 hcol-quarters x 64 batch-groups

typedef __attribute__((ext_vector_type(8))) short bf16x8;
typedef __attribute__((ext_vector_type(4))) float f32x4;
typedef __attribute__((ext_vector_type(4))) int   i32x4;

__device__ __forceinline__ unsigned short f2bf(float f) {
    union { float f; unsigned int u; } v; v.f = f;
    unsigned int u = v.u;
    unsigned int r = (u + 0x7FFFu + ((u >> 16) & 1u)) >> 16;  // RNE
    return (unsigned short)r;
}
__device__ __forceinline__ float sig_fast(float x) {
    return __builtin_amdgcn_rcpf(1.0f + __builtin_amdgcn_exp2f(-1.4426950408889634f * x));
}
__device__ __forceinline__ float tanh_fast(float x) {
    return 1.0f - 2.0f * __builtin_amdgcn_rcpf(__builtin_amdgcn_exp2f(2.8853900817779268f * x) + 1.0f);
}
__device__ __forceinline__ f32x4 mfma_v(i32x4 a, i32x4 b, f32x4 c) {
    return __builtin_amdgcn_mfma_f32_16x16x32_bf16(
        __builtin_bit_cast(bf16x8, a), __builtin_bit_cast(bf16x8, b), c, 0, 0, 0);
}

// ---------------------------------------------------------------------------
// K1: swizzled bf16 weights [kit][ntile][lane] x 16B + zero the 2 MB hxc
// (seq words must start != any expected step; zero works, expected >= 1).
// ---------------------------------------------------------------------------
__global__ __launch_bounds__(64) void build_wswz(
    const float* __restrict__ Wgx, const float* __restrict__ Wgh, const float* __restrict__ bg,
    const float* __restrict__ Wix, const float* __restrict__ Wih, const float* __restrict__ bi,
    const float* __restrict__ Wfx, const float* __restrict__ Wfh, const float* __restrict__ bf_,
    const float* __restrict__ Wox, const float* __restrict__ Woh, const float* __restrict__ bo,
    unsigned short* __restrict__ wswz, unsigned int* __restrict__ hxcz)
{
    {
        int4 z4 = {0, 0, 0, 0};
        size_t gid = (size_t)blockIdx.x * 64 + threadIdx.x;
        for (size_t i = gid; i < 131072; i += (size_t)NBLK_K1 * 64)
            ((int4*)hxcz)[i] = z4;
    }

    int g   = blockIdx.x / NKIT;   // ntile
    int kit = blockIdx.x % NKIT;
    int lane = threadIdx.x;
    int n = g * 16 + (lane & 15);
    int q = n >> 8;
    int col = n & 255;
    const float* Wh = (q == 0) ? Wgh : (q == 1) ? Wih : (q == 2) ? Wfh : Woh;
    const float* Wx = (q == 0) ? Wgx : (q == 1) ? Wix : (q == 2) ? Wfx : Wox;
    const float* bb = (q == 0) ? bg  : (q == 1) ? bi  : (q == 2) ? bf_ : bo;
    int k0 = kit * 32 + (lane >> 4) * 8;

    int4 out;
    unsigned short* p = (unsigned short*)&out;
#pragma unroll
    for (int jx = 0; jx < 8; jx++) {
        int k = k0 + jx;
        float v = 0.0f;
        if (k < 256)             v = Wh[k * 256 + col];
        else if (k < 256 + EMBD) v = Wx[(k - 256) * 256 + col];
        else if (k == 266)       v = bb[col];
        p[jx] = f2bf(v);
    }
    ((int4*)wswz)[(kit * 64 + g) * 64 + lane] = out;
}

// kit -> B source (compile-time s,g only; rule 20: no runtime indexing)
#define KIDX(s) ((s) == 7 ? 5 : (s))
#define BSRC(s, g) ((s) == 5 ? B_lds[(0 * 16 + (g) * 4 + j) * 64 + lane] \
                  : (s) == 6 ? B_lds[(1 * 16 + (g) * 4 + j) * 64 + lane] \
                  : breg[KIDX(s)][(g)])
#define DO_KIT(s) do { i32x4 a_ = ((const i32x4*)Ah_lds)[ah_rd + (s) * 4]; \
        acc0 = mfma_v(a_, BSRC(s, 0), acc0); \
        acc1 = mfma_v(a_, BSRC(s, 1), acc1); \
        acc2 = mfma_v(a_, BSRC(s, 2), acc2); \
        acc3 = mfma_v(a_, BSRC(s, 3), acc3); } while (0)

// ---------------------------------------------------------------------------
// K2: 4-way N-SPLIT persistent LSTM, ALL-GATES-PER-WAVE repartition (R33
// structure, resubmitted after container death with hang-risk collapsed:
// spin bound 200000 -> 20000 so even a total protocol failure finishes in
// ~1.7s with wrong output + counters instead of killing the container, and
// waves_per_eu(1,1) -> min-only (1), the only never-before-run attribute).
// 256 blocks x 256 threads (4 waves, 1/SIMD, 1 block/CU).
// Wave j owns hcol ntile j (16 cols) x ALL 4 gates: 36 MFMAs/step as 4
// independent 9-chains. MFMA C layout (row=(lane>>4)*4+r, col=lane&15)
// puts all 4 gate-z for (row,col) IN ONE LANE -> gate math fully
// in-register: R31's z_lds round-trip + B1 barrier DELETED (2 barriers/step).
// Exchange: R30/31-verified seq-tagged u64, fire-and-forget sc1, combined
// retry -- COL-MAJOR row-pair packing (lane holds 4 rows x 1 col):
// u64 {hi: seq, lo: pack(h[2rp], h[2rp+1])}; producer stores ONE dwordx4
// (2 tagged u64); consumers transpose during LDS staging (12 ds_write_b16).
// af layout unchanged (row-major Ah_lds).
// ---------------------------------------------------------------------------
__global__ __launch_bounds__(256)
__attribute__((amdgpu_waves_per_eu(1)))
void lstm_main(
    const int*   __restrict__ xtok,   // [1024][1][256]
    const float* __restrict__ emb,    // [32000][10]
    const float* __restrict__ Wph,    // [256][10]
    const float* __restrict__ bp,     // [10]
    const unsigned short* __restrict__ wswz,
    unsigned long long* __restrict__ hxc,  // [2][64][256 col][8 rowpair] u64
    float* __restrict__ out)          // [1024][10]
{
    __shared__ __align__(16) unsigned short A8_lds[2][64 * 8];  // 2 KB (kit 8: x+bias)
    __shared__ __align__(16) i32x4 B_lds[2 * 16 * 64];          // 32 KB (kits 5,6)
    __shared__ __align__(16) unsigned int Ah_lds[16 * 132];     // 8.25 KB (h, padded)
    __shared__ float hbuf[16][68];                              // 4.25 KB (epilogue)
    __shared__ float outacc[160];

    const int tid  = threadIdx.x;
    const int j    = tid >> 6;        // wave = hcol ntile 0..3
    const int lane = tid & 63;
    const int qq   = lane >> 4;       // row quad 0..3
    const int col15 = lane & 15;
    const int blk  = blockIdx.x;
    const int gb   = blk & 63;        // batch group
    const int hg   = blk >> 6;        // hcol quarter 0..3

    const int m_x = tid >> 4;         // x-gather row
    const int e_x = tid & 15;

    const i32x4* Bg = (const i32x4*)wswz;

    // --- B prologue: regs for kits {0,1,2,3,4,7,8} x 4 gates (112 VGPRs) ---
    i32x4 breg[7][4];
    {
        const int ks[7] = {0, 1, 2, 3, 4, 7, 8};
#pragma unroll
        for (int i = 0; i < 7; i++)
#pragma unroll
            for (int g = 0; g < 4; g++)
                breg[i][g] = Bg[(ks[i] * 64 + g * 16 + hg * 4 + j) * 64 + lane];
    }
    // --- B LDS: kits 5,6 for this block's 16 ntiles ---
    for (int i = tid; i < 2 * 16 * 64; i += 256) {
        int k   = i >> 10;          // 0->kit5, 1->kit6
        int ntl = (i >> 6) & 15;    // local ntile = g*4 + jj
        int ln  = i & 63;
        int g_ = ntl >> 2, jj = ntl & 3;
        B_lds[i] = Bg[((5 + k) * 64 + g_ * 16 + hg * 4 + jj) * 64 + ln];
    }

    // --- A8 init: zeros, bias (both parities), x_0 (parity 0) ---
    {
        int4 z4 = {0, 0, 0, 0};
        if (tid < 128) ((int4*)A8_lds)[tid] = z4;
    }
    __syncthreads();
    if (tid < 16) {
        A8_lds[0][(16 + tid) * 8 + 2] = 0x3F80;  // bias=1.0 at k-local=10
        A8_lds[1][(16 + tid) * 8 + 2] = 0x3F80;
    }
    if (e_x < EMBD) {
        int tok = xtok[(gb * 16 + m_x) * T_STEPS + 0];
        float v = emb[tok * EMBD + e_x];
        A8_lds[0][(m_x + 16 * (e_x >> 3)) * 8 + (e_x & 7)] = f2bf(v);
    }
    __syncthreads();

    float c0 = 0.f, c1 = 0.f, c2 = 0.f, c3 = 0.f;  // c for rows 4q..4q+3, own col

    // af LDS read base (i32x4 units): row (lane&15)*33 + quad; kit s at +4s
    const int ah_rd = (lane & 15) * 33 + (lane >> 4);
    // staging map: thread t -> col c_loc = t>>2, rowpair base rp0 = (t&3)*2
    const int c_loc = tid >> 2;
    const int rp0   = (tid & 3) * 2;
    const int rq0 = (hg + 1) & 3, rq1 = (hg + 2) & 3, rq2 = (hg + 3) & 3;
    const int c_own = hg * 64 + j * 16 + col15;
    unsigned short* AhS = (unsigned short*)Ah_lds;

    for (int t = 0; t < T_STEPS; t++) {
        const int p = t & 1, q = (t + 1) & 1;

        // x(t+1) prefetch (independent)
        float xval = 0.0f;
        const bool do_x = (t < T_STEPS - 1) && (e_x < EMBD);
        if (t < T_STEPS - 1) {
            int tok = xtok[(gb * 16 + m_x) * T_STEPS + (t + 1)];
            if (e_x < EMBD) xval = emb[tok * EMBD + e_x];
        }

        const unsigned long long* hb = hxc + (size_t)(p * 64 + gb) * 2048;
        const unsigned long long* a0 = hb + (rq0 * 64 + c_loc) * 8 + rp0;
        const unsigned long long* a1 = hb + (rq1 * 64 + c_loc) * 8 + rp0;
        const unsigned long long* a2 = hb + (rq2 * 64 + c_loc) * 8 + rp0;
        i32x4 va, vb, vc;

        // ISSUE remote h(t) loads -- no wait, in flight across the barrier
        if (t > 0) {
            asm volatile("global_load_dwordx4 %0, %3, off sc1\n\t"
                         "global_load_dwordx4 %1, %4, off sc1\n\t"
                         "global_load_dwordx4 %2, %5, off sc1"
                         : "=&v"(va), "=&v"(vb), "=&v"(vc)
                         : "v"(a0), "v"(a1), "v"(a2) : "memory");
        }

        // LAND-own: raw barrier, LDS-only wait (keeps vmem in flight)
        asm volatile("s_waitcnt lgkmcnt(0)" ::: "memory");
        __builtin_amdgcn_s_barrier();

        f32x4 acc0 = (f32x4){0.f, 0.f, 0.f, 0.f};
        f32x4 acc1 = (f32x4){0.f, 0.f, 0.f, 0.f};
        f32x4 acc2 = (f32x4){0.f, 0.f, 0.f, 0.f};
        f32x4 acc3 = (f32x4){0.f, 0.f, 0.f, 0.f};
        // kit 8 (x + bias) -- h-independent, one per gate
        {
            i32x4 a8 = ((const i32x4*)A8_lds[p])[lane];
            acc0 = mfma_v(a8, breg[6][0], acc0);
            acc1 = mfma_v(a8, breg[6][1], acc1);
            acc2 = mfma_v(a8, breg[6][2], acc2);
            acc3 = mfma_v(a8, breg[6][3], acc3);
        }

        if (t > 0) {
            // own kits {2hg, 2hg+1} (h local in LDS from our tail) under the RT
            if      (hg == 0) { DO_KIT(0); DO_KIT(1); }
            else if (hg == 1) { DO_KIT(2); DO_KIT(3); }
            else if (hg == 2) { DO_KIT(4); DO_KIT(5); }
            else              { DO_KIT(6); DO_KIT(7); }

            // validate: wait threaded through va/vb/vc (orders reg reads)
            asm volatile("s_waitcnt vmcnt(0)"
                         : "+v"(va), "+v"(vb), "+v"(vc) :: "memory");
            int spins = 0;
            while ((va.y != t || va.w != t || vb.y != t || vb.w != t ||
                    vc.y != t || vc.w != t) && spins < 20000) {
                ++spins;
                __builtin_amdgcn_s_sleep(1);
                asm volatile("global_load_dwordx4 %0, %3, off sc1\n\t"
                             "global_load_dwordx4 %1, %4, off sc1\n\t"
                             "global_load_dwordx4 %2, %5, off sc1\n\t"
                             "s_waitcnt vmcnt(0)"
                             : "=&v"(va), "=&v"(vb), "=&v"(vc)
                             : "v"(a0), "v"(a1), "v"(a2) : "memory");
            }
            // transpose-land: u64 {seq, pack(h[2rp],h[2rp+1])} -> row-major Ah
            {
                const int r0 = 2 * rp0;  // rows r0..r0+3, col (rq*64 + c_loc)
                int cg0 = rq0 * 64 + c_loc;
                AhS[(r0 + 0) * 264 + cg0] = (unsigned short)(va.x & 0xffff);
                AhS[(r0 + 1) * 264 + cg0] = (unsigned short)((unsigned)va.x >> 16);
                AhS[(r0 + 2) * 264 + cg0] = (unsigned short)(va.z & 0xffff);
                AhS[(r0 + 3) * 264 + cg0] = (unsigned short)((unsigned)va.z >> 16);
                int cg1 = rq1 * 64 + c_loc;
                AhS[(r0 + 0) * 264 + cg1] = (unsigned short)(vb.x & 0xffff);
                AhS[(r0 + 1) * 264 + cg1] = (unsigned short)((unsigned)vb.x >> 16);
                AhS[(r0 + 2) * 264 + cg1] = (unsigned short)(vb.z & 0xffff);
                AhS[(r0 + 3) * 264 + cg1] = (unsigned short)((unsigned)vb.z >> 16);
                int cg2 = rq2 * 64 + c_loc;
                AhS[(r0 + 0) * 264 + cg2] = (unsigned short)(vc.x & 0xffff);
                AhS[(r0 + 1) * 264 + cg2] = (unsigned short)((unsigned)vc.x >> 16);
                AhS[(r0 + 2) * 264 + cg2] = (unsigned short)(vc.z & 0xffff);
                AhS[(r0 + 3) * 264 + cg2] = (unsigned short)((unsigned)vc.z >> 16);
            }
            // LAND-remote: raw barrier, LDS-only wait
            asm volatile("s_waitcnt lgkmcnt(0)" ::: "memory");
            __builtin_amdgcn_s_barrier();

            // 6 remote kits
            if (hg != 0) { DO_KIT(0); DO_KIT(1); }
            if (hg != 1) { DO_KIT(2); DO_KIT(3); }
            if (hg != 2) { DO_KIT(4); DO_KIT(5); }
            if (hg != 3) { DO_KIT(6); DO_KIT(7); }
        }

        // gate math FULLY IN REGISTERS: all 4 gate-z for (row,col) in-lane.
        // rows m = qq*4 + r, col c_own; z_g=acc0, z_i=acc1, z_f=acc2, z_o=acc3
        float h0, h1, h2, h3;
        {
            float gg, ii, ff, oo, cn;
            gg = tanh_fast(acc0[0]); ii = sig_fast(acc1[0]);
            ff = sig_fast(acc2[0]);  oo = sig_fast(acc3[0]);
            cn = gg * ii + c0 * ff; c0 = cn; h0 = tanh_fast(cn) * oo;
            gg = tanh_fast(acc0[1]); ii = sig_fast(acc1[1]);
            ff = sig_fast(acc2[1]);  oo = sig_fast(acc3[1]);
            cn = gg * ii + c1 * ff; c1 = cn; h1 = tanh_fast(cn) * oo;
            gg = tanh_fast(acc0[2]); ii = sig_fast(acc1[2]);
            ff = sig_fast(acc2[2]);  oo = sig_fast(acc3[2]);
            cn = gg * ii + c2 * ff; c2 = cn; h2 = tanh_fast(cn) * oo;
            gg = tanh_fast(acc0[3]); ii = sig_fast(acc1[3]);
            ff = sig_fast(acc2[3]);  oo = sig_fast(acc3[3]);
            cn = gg * ii + c3 * ff; c3 = cn; h3 = tanh_fast(cn) * oo;
        }

        if (t < T_STEPS - 1) {
            unsigned int p01, p23;
            asm("v_cvt_pk_bf16_f32 %0, %1, %2" : "=v"(p01) : "v"(h0), "v"(h1));
            asm("v_cvt_pk_bf16_f32 %0, %1, %2" : "=v"(p23) : "v"(h2), "v"(h3));
            // own col straight to LDS (rows 4q..4q+3), consumed after next LAND-own
            AhS[(4 * qq + 0) * 264 + c_own] = (unsigned short)(p01 & 0xffff);
            AhS[(4 * qq + 1) * 264 + c_own] = (unsigned short)(p01 >> 16);
            AhS[(4 * qq + 2) * 264 + c_own] = (unsigned short)(p23 & 0xffff);
            AhS[(4 * qq + 3) * 264 + c_own] = (unsigned short)(p23 >> 16);
            if (do_x)
                A8_lds[q][(m_x + 16 * (e_x >> 3)) * 8 + (e_x & 7)] = f2bf(xval);
            // fire-and-forget: ONE dwordx4 = 2 tagged u64 (rowpairs 2q, 2q+1)
            i32x4 pv;
            pv.x = (int)p01; pv.y = t + 1; pv.z = (int)p23; pv.w = t + 1;
            unsigned long long* dst =
                hxc + (size_t)(q * 64 + gb) * 2048 + (size_t)c_own * 8 + 2 * qq;
            asm volatile("global_store_dwordx4 %0, %1, off sc1"
                         :: "v"(dst), "v"(pv) : "memory");
        } else {
            // --- epilogue: h held in h0..h3 (rows 4q+r, col c_own) ---
            hbuf[4 * qq + 0][j * 16 + col15] = h0;
            hbuf[4 * qq + 1][j * 16 + col15] = h1;
            hbuf[4 * qq + 2][j * 16 + col15] = h2;
            hbuf[4 * qq + 3][j * 16 + col15] = h3;
            if (tid < 160) outacc[tid] = 0.0f;
            __syncthreads();
            if (tid < 160) {
                int m = tid / 10, cl = tid - m * 10;
                float s = 0.0f;
#pragma unroll 8
                for (int c = 0; c < 64; c++)
                    s += hbuf[m][c] * Wph[(hg * 64 + c) * 10 + cl];
                if (hg == 0) s += bp[cl];     // bias added exactly once per row
                atomicAdd(&out[(gb * 16 + m) * 10 + cl], s);
            }
        }
    }
}

extern "C" void kernel_launch(void* const* d_in, const int* in_sizes, int n_in,
                              void* d_out, int out_size, void* d_ws, size_t ws_size,
                              hipStream_t stream) {
    const int*   x    = (const int*)  d_in[0];
    const float* emb  = (const float*)d_in[1];
    const float* Wgx  = (const float*)d_in[2];
    const float* Wgh  = (const float*)d_in[3];
    const float* bg   = (const float*)d_in[4];
    const float* Wix  = (const float*)d_in[5];
    const float* Wih  = (const float*)d_in[6];
    const float* bi   = (const float*)d_in[7];
    const float* Wfx  = (const float*)d_in[8];
    const float* Wfh  = (const float*)d_in[9];
    const float* bf_  = (const float*)d_in[10];
    const float* Wox  = (const float*)d_in[11];
    const float* Woh  = (const float*)d_in[12];
    const float* bo   = (const float*)d_in[13];
    const float* Wph  = (const float*)d_in[14];
    const float* bp   = (const float*)d_in[15];

    char* ws = (char*)d_ws;
    unsigned short*     wswz = (unsigned short*)ws;                 // 576 KB
    unsigned long long* hxc  = (unsigned long long*)(ws + 589824 + 4096); // 2 MB

    build_wswz<<<NBLK_K1, 64, 0, stream>>>(Wgx, Wgh, bg, Wix, Wih, bi,
                                           Wfx, Wfh, bf_, Wox, Woh, bo,
                                           wswz, (unsigned int*)hxc);
    lstm_main<<<NBLK, 256, 0, stream>>>(x, emb, Wph, bp, wswz, hxc,
                                        (float*)d_out);
}